// Round 6
// baseline (733.192 us; speedup 1.0000x reference)
//
#include <hip/hip_runtime.h>
#include <math.h>

// NetNew_17162689315115: 8-layer EQL-style net, B=524288 rows.
// Reference is numpy float64; the map is chaotic (sin/cos at |z|~1e8), so the
// ENTIRE chain runs in fp64 (round 3+: passed, absmax 1.245e6 / thr 1.65e6).
// DO NOT reassociate the matmul or touch precision — bitwise-frozen numerics:
// each z[j] accumulates fma(W[j,k], h[k]) in ascending-k order.
//
// Round 6: revert to j-outer matmul (round 4's shape — round 5's interchange
// made z[13] live across the k-loop and blew scratch out to HBM: WRITE_SIZE
// 2MB->21MB, dur 407->450). New: amdgpu_waves_per_eu(2,2) pins the register
// allocator's occupancy TARGET at 2 waves/EU (launch_bounds' 2nd arg is only
// a min — rounds 4/5 still allocated 104-112 VGPRs and spilled the ~190-reg
// live set). h[80] is irreducibly live (every layer reads [BASE,80)), so the
// right config is 256 VGPRs / zero spill / 2 waves per EU.

static constexpr double MAX_MLT   = 99999999.0;
static constexpr double MAX_DIV   = 9999.0;
static constexpr double MAX_EXP_C = 17.0;
static constexpr double MIN_DENOM = 0.0001;

static constexpr int IN0  = 8;   // vari_num + const_num
static constexpr int VDIM = 13;  // rows of each W
static constexpr int NOPS = 9;   // ops appended per layer
static constexpr int FDIM = 80;  // final h dim: 8 + 8*9

// layer weight element counts and fp64 workspace offsets
// in_dims: 8,17,26,35,44,53,62,71 ; W_i is 13 x in_dim ; Wf is 1 x 80
static constexpr int WSZ[9]  = {104, 221, 338, 455, 572, 689, 806, 923, 80};
static constexpr int WOFF[9] = {0, 104, 325, 663, 1118, 1690, 2379, 3185, 4108};

// ---- prep: widen fp32 weights -> fp64 workspace (exact, bitwise-neutral) ----
__global__ void widen_kernel(const float* __restrict__ s0, const float* __restrict__ s1,
                             const float* __restrict__ s2, const float* __restrict__ s3,
                             const float* __restrict__ s4, const float* __restrict__ s5,
                             const float* __restrict__ s6, const float* __restrict__ s7,
                             const float* __restrict__ s8, double* __restrict__ dst) {
    int seg = blockIdx.y;
    int i   = blockIdx.x * blockDim.x + threadIdx.x;
    const float* src;
    switch (seg) {
        case 0: src = s0; break; case 1: src = s1; break; case 2: src = s2; break;
        case 3: src = s3; break; case 4: src = s4; break; case 5: src = s5; break;
        case 6: src = s6; break; case 7: src = s7; break; default: src = s8; break;
    }
    if (i < WSZ[seg]) dst[WOFF[seg] + i] = (double)src[i];
}

// _clip_mag forward, float64: scale = |mx/v|, o = where(|v|>=mx, v*scale, v).
// NaN passes through (compare false), matching jnp.where.
__device__ __forceinline__ double clip_ref(double v, double mx) {
    double scale = fabs(mx / v);
    double vs    = v * scale;
    return (fabs(v) >= mx) ? vs : v;
}

template<int IN_DIM, int BASE>
__device__ __forceinline__ void layer_step(const double* __restrict__ W,
                                           double (&h)[FDIM]) {
    double z[VDIM];
    #pragma unroll
    for (int j = 0; j < VDIM; ++j) {
        double acc = 0.0;
        #pragma unroll
        for (int k = 0; k < IN_DIM; ++k) {
            acc = fma(W[j * IN_DIM + k], h[BASE + k], acc);  // frozen accum order
        }
        z[j] = acc;
    }
    constexpr int BO = BASE - NOPS;
    // op order: + - * / sin cos exp log square, consuming z cols in order
    h[BO + 0] = z[0] + z[1];
    h[BO + 1] = z[2] - z[3];
    h[BO + 2] = clip_ref(z[4] * z[5], MAX_MLT);
    {
        double b     = z[7];
        double denom = (b == 0.0) ? (b + MIN_DENOM) : b;
        h[BO + 3]    = clip_ref(z[6] / denom, MAX_DIV);
    }
    h[BO + 4] = sin(z[8]);
    h[BO + 5] = cos(z[9]);
    {
        double a    = z[10];
        double safe = (a >= MAX_EXP_C) ? (a * (MAX_EXP_C / a)) : a;
        h[BO + 6]   = exp(safe);
    }
    h[BO + 7] = log(fabs(z[11]));
    h[BO + 8] = clip_ref(z[12] * z[12], MAX_MLT);
}

__global__ void __launch_bounds__(256)
__attribute__((amdgpu_waves_per_eu(2, 2)))
net_kernel(const float* __restrict__ x, const double* __restrict__ Wd,
           float* __restrict__ out, int nrows) {
    int row = blockIdx.x * blockDim.x + threadIdx.x;
    if (row >= nrows) return;

    double h[FDIM];

    // x occupies the TAIL of the final feature vector (each layer prepends).
    const float4* x4 = reinterpret_cast<const float4*>(x);
    float4 xa = x4[row * 2 + 0];
    float4 xb = x4[row * 2 + 1];
    h[72] = (double)xa.x; h[73] = (double)xa.y; h[74] = (double)xa.z; h[75] = (double)xa.w;
    h[76] = (double)xb.x; h[77] = (double)xb.y; h[78] = (double)xb.z; h[79] = (double)xb.w;

    layer_step<IN0 + 0 * NOPS, 72>(Wd + WOFF[0], h);  // in_dim  8, write at 63
    layer_step<IN0 + 1 * NOPS, 63>(Wd + WOFF[1], h);  // in_dim 17, write at 54
    layer_step<IN0 + 2 * NOPS, 54>(Wd + WOFF[2], h);  // in_dim 26, write at 45
    layer_step<IN0 + 3 * NOPS, 45>(Wd + WOFF[3], h);  // in_dim 35, write at 36
    layer_step<IN0 + 4 * NOPS, 36>(Wd + WOFF[4], h);  // in_dim 44, write at 27
    layer_step<IN0 + 5 * NOPS, 27>(Wd + WOFF[5], h);  // in_dim 53, write at 18
    layer_step<IN0 + 6 * NOPS, 18>(Wd + WOFF[6], h);  // in_dim 62, write at  9
    layer_step<IN0 + 7 * NOPS,  9>(Wd + WOFF[7], h);  // in_dim 71, write at  0

    const double* Wf = Wd + WOFF[8];
    double acc = 0.0;
    #pragma unroll
    for (int k = 0; k < FDIM; ++k) {
        acc = fma(Wf[k], h[k], acc);
    }
    out[row] = (float)acc;
}

extern "C" void kernel_launch(void* const* d_in, const int* in_sizes, int n_in,
                              void* d_out, int out_size, void* d_ws, size_t ws_size,
                              hipStream_t stream) {
    const float* x = (const float*)d_in[0];
    double* Wd     = (double*)d_ws;   // 4188 doubles = 33.5 KB
    float* out     = (float*)d_out;

    // widen weights (d_ws is re-poisoned before every call -> must rewrite)
    {
        dim3 grid((923 + 255) / 256, 9);
        widen_kernel<<<grid, 256, 0, stream>>>(
            (const float*)d_in[1], (const float*)d_in[2], (const float*)d_in[3],
            (const float*)d_in[4], (const float*)d_in[5], (const float*)d_in[6],
            (const float*)d_in[7], (const float*)d_in[8], (const float*)d_in[9],
            Wd);
    }

    int nrows = in_sizes[0] / IN0;
    int block = 256;
    int grid  = (nrows + block - 1) / block;
    net_kernel<<<grid, block, 0, stream>>>(x, Wd, out, nrows);
}

// Round 7
// 465.991 us; speedup vs baseline: 1.5734x; 1.5734x over previous
//
#include <hip/hip_runtime.h>
#include <math.h>

// NetNew_17162689315115: 8-layer EQL-style net, B=524288 rows.
// Reference is numpy float64; the map is chaotic (sin/cos at |z|~1e8), so the
// ENTIRE chain runs in fp64 (passed since round 3: absmax 1.245e6 / thr 1.65e6,
// bit-stable across rounds 3-6). DO NOT reassociate the matmul or touch
// precision — each z[j] accumulates fma(W[j,k], h[k]) in ascending-k order.
//
// Round 7: EXACT round-4 code (407 us proven: j-outer matmul, plain
// __launch_bounds__, fp64 weights pre-widened into d_ws) with ONE change:
// block size 256 -> 64. R4 showed VGPR=112 yet only ~2 resident blocks/CU
// (23% occupancy, 65% VALUBusy, ~265 us VALU busy-time = the 4188-FMA fp64
// floor). If residency is capped per-BLOCK, 64-thread blocks pack 4x finer
// and close the 35% idle gap; if capped per-wave, dur stays ~407 (clean
// falsification). Allocator hints (waves_per_eu, launch_bounds min) were
// tried R5/R6 and regressed — do not reintroduce them.

static constexpr double MAX_MLT   = 99999999.0;
static constexpr double MAX_DIV   = 9999.0;
static constexpr double MAX_EXP_C = 17.0;
static constexpr double MIN_DENOM = 0.0001;

static constexpr int IN0  = 8;   // vari_num + const_num
static constexpr int VDIM = 13;  // rows of each W
static constexpr int NOPS = 9;   // ops appended per layer
static constexpr int FDIM = 80;  // final h dim: 8 + 8*9

// layer weight element counts and fp64 workspace offsets
// in_dims: 8,17,26,35,44,53,62,71 ; W_i is 13 x in_dim ; Wf is 1 x 80
static constexpr int WSZ[9]  = {104, 221, 338, 455, 572, 689, 806, 923, 80};
static constexpr int WOFF[9] = {0, 104, 325, 663, 1118, 1690, 2379, 3185, 4108};

// ---- prep: widen fp32 weights -> fp64 workspace (exact, bitwise-neutral) ----
__global__ void widen_kernel(const float* __restrict__ s0, const float* __restrict__ s1,
                             const float* __restrict__ s2, const float* __restrict__ s3,
                             const float* __restrict__ s4, const float* __restrict__ s5,
                             const float* __restrict__ s6, const float* __restrict__ s7,
                             const float* __restrict__ s8, double* __restrict__ dst) {
    int seg = blockIdx.y;
    int i   = blockIdx.x * blockDim.x + threadIdx.x;
    const float* src;
    switch (seg) {
        case 0: src = s0; break; case 1: src = s1; break; case 2: src = s2; break;
        case 3: src = s3; break; case 4: src = s4; break; case 5: src = s5; break;
        case 6: src = s6; break; case 7: src = s7; break; default: src = s8; break;
    }
    if (i < WSZ[seg]) dst[WOFF[seg] + i] = (double)src[i];
}

// _clip_mag forward, float64: scale = |mx/v|, o = where(|v|>=mx, v*scale, v).
// NaN passes through (compare false), matching jnp.where.
__device__ __forceinline__ double clip_ref(double v, double mx) {
    double scale = fabs(mx / v);
    double vs    = v * scale;
    return (fabs(v) >= mx) ? vs : v;
}

template<int IN_DIM, int BASE>
__device__ __forceinline__ void layer_step(const double* __restrict__ W,
                                           double (&h)[FDIM]) {
    double z[VDIM];
    #pragma unroll
    for (int j = 0; j < VDIM; ++j) {
        double acc = 0.0;
        #pragma unroll
        for (int k = 0; k < IN_DIM; ++k) {
            acc = fma(W[j * IN_DIM + k], h[BASE + k], acc);  // frozen accum order
        }
        z[j] = acc;
    }
    constexpr int BO = BASE - NOPS;
    // op order: + - * / sin cos exp log square, consuming z cols in order
    h[BO + 0] = z[0] + z[1];
    h[BO + 1] = z[2] - z[3];
    h[BO + 2] = clip_ref(z[4] * z[5], MAX_MLT);
    {
        double b     = z[7];
        double denom = (b == 0.0) ? (b + MIN_DENOM) : b;
        h[BO + 3]    = clip_ref(z[6] / denom, MAX_DIV);
    }
    h[BO + 4] = sin(z[8]);
    h[BO + 5] = cos(z[9]);
    {
        double a    = z[10];
        double safe = (a >= MAX_EXP_C) ? (a * (MAX_EXP_C / a)) : a;
        h[BO + 6]   = exp(safe);
    }
    h[BO + 7] = log(fabs(z[11]));
    h[BO + 8] = clip_ref(z[12] * z[12], MAX_MLT);
}

__global__ void __launch_bounds__(64)
net_kernel(const float* __restrict__ x, const double* __restrict__ Wd,
           float* __restrict__ out, int nrows) {
    int row = blockIdx.x * blockDim.x + threadIdx.x;
    if (row >= nrows) return;

    double h[FDIM];

    // x occupies the TAIL of the final feature vector (each layer prepends).
    const float4* x4 = reinterpret_cast<const float4*>(x);
    float4 xa = x4[row * 2 + 0];
    float4 xb = x4[row * 2 + 1];
    h[72] = (double)xa.x; h[73] = (double)xa.y; h[74] = (double)xa.z; h[75] = (double)xa.w;
    h[76] = (double)xb.x; h[77] = (double)xb.y; h[78] = (double)xb.z; h[79] = (double)xb.w;

    layer_step<IN0 + 0 * NOPS, 72>(Wd + WOFF[0], h);  // in_dim  8, write at 63
    layer_step<IN0 + 1 * NOPS, 63>(Wd + WOFF[1], h);  // in_dim 17, write at 54
    layer_step<IN0 + 2 * NOPS, 54>(Wd + WOFF[2], h);  // in_dim 26, write at 45
    layer_step<IN0 + 3 * NOPS, 45>(Wd + WOFF[3], h);  // in_dim 35, write at 36
    layer_step<IN0 + 4 * NOPS, 36>(Wd + WOFF[4], h);  // in_dim 44, write at 27
    layer_step<IN0 + 5 * NOPS, 27>(Wd + WOFF[5], h);  // in_dim 53, write at 18
    layer_step<IN0 + 6 * NOPS, 18>(Wd + WOFF[6], h);  // in_dim 62, write at  9
    layer_step<IN0 + 7 * NOPS,  9>(Wd + WOFF[7], h);  // in_dim 71, write at  0

    const double* Wf = Wd + WOFF[8];
    double acc = 0.0;
    #pragma unroll
    for (int k = 0; k < FDIM; ++k) {
        acc = fma(Wf[k], h[k], acc);
    }
    out[row] = (float)acc;
}

extern "C" void kernel_launch(void* const* d_in, const int* in_sizes, int n_in,
                              void* d_out, int out_size, void* d_ws, size_t ws_size,
                              hipStream_t stream) {
    const float* x = (const float*)d_in[0];
    double* Wd     = (double*)d_ws;   // 4188 doubles = 33.5 KB
    float* out     = (float*)d_out;

    // widen weights (d_ws is re-poisoned before every call -> must rewrite)
    {
        dim3 grid((923 + 255) / 256, 9);
        widen_kernel<<<grid, 256, 0, stream>>>(
            (const float*)d_in[1], (const float*)d_in[2], (const float*)d_in[3],
            (const float*)d_in[4], (const float*)d_in[5], (const float*)d_in[6],
            (const float*)d_in[7], (const float*)d_in[8], (const float*)d_in[9],
            Wd);
    }

    int nrows = in_sizes[0] / IN0;
    int block = 64;
    int grid  = (nrows + block - 1) / block;
    net_kernel<<<grid, block, 0, stream>>>(x, Wd, out, nrows);
}